// Round 8
// baseline (228.971 us; speedup 1.0000x reference)
//
#include <hip/hip_runtime.h>
#include <hip/hip_bf16.h>

using bf16 = __hip_bfloat16;
typedef __attribute__((ext_vector_type(8))) short short8;   // 8 bf16 = 4 VGPRs (MFMA A/B frag)
typedef __attribute__((ext_vector_type(4))) float floatx4;  // MFMA C/D frag

#define B_  2
#define T_  2048
#define C_  1024
#define H_  16
#define HD_ 64
#define BT_ (B_*T_)
#define NX_ ((size_t)BT_*C_)   /* 4M elems */
#define NW_ ((size_t)C_*C_)    /* 1M elems */
#define PSTR 136               /* Ps row stride in elems: 272B, 16B-aligned */
#define KSCQ 0.1803368801f     /* (1/sqrt(64)) * log2(e), folded into Q at qkv epilogue */

// async global->LDS, 16B per lane. LDS dest is wave-uniform base; lane i lands at base + i*16B.
__device__ __forceinline__ void gl2lds16(const bf16* g, bf16* l) {
    __builtin_amdgcn_global_load_lds((const __attribute__((address_space(1))) unsigned int*)g,
                                     (__attribute__((address_space(3))) unsigned int*)l,
                                     16, 0, 0);
}

// ---------------------------------------------------------------------------
// Kernel 0: f32 -> bf16 conversion for x and the 4 weight matrices.
// ---------------------------------------------------------------------------
__global__ __launch_bounds__(256) void cvt_f32_bf16(
    const float* __restrict__ x,
    const float* __restrict__ Wq, const float* __restrict__ Wk,
    const float* __restrict__ Wv, const float* __restrict__ Wp,
    bf16* __restrict__ xb, bf16* __restrict__ wqb, bf16* __restrict__ wkb,
    bf16* __restrict__ wvb, bf16* __restrict__ wpb)
{
    size_t i4 = ((size_t)blockIdx.x * 256 + threadIdx.x) * 4;
    const float* src; bf16* dst; size_t off;
    if (i4 < NX_) { src = x; dst = xb; off = i4; }
    else {
        size_t j = i4 - NX_;
        int r = (int)(j >> 20);
        off = j & (NW_ - 1);
        src = (r==0) ? Wq : (r==1) ? Wk : (r==2) ? Wv : Wp;
        dst = (r==0) ? wqb : (r==1) ? wkb : (r==2) ? wvb : wpb;
    }
    float4 v = *(const float4*)(src + off);
    union { bf16 h[4]; uint2 u; } o;
    o.h[0] = __float2bfloat16(v.x); o.h[1] = __float2bfloat16(v.y);
    o.h[2] = __float2bfloat16(v.z); o.h[3] = __float2bfloat16(v.w);
    *(uint2*)(dst + off) = o.u;
}

// ---------------------------------------------------------------------------
// Kernel A: fused QKV projection.  y = x @ W^T + b for W in {Wq,Wk,Wv}.
// Grid (32 mtiles, 24 ntiles). ntile/8 selects the weight. 128x128 tile, BK=32.
// Q stored PRE-SCALED by KSCQ; Q,K stored [B,T,C]; V stored [B,H,HD,T].
// ---------------------------------------------------------------------------
__global__ __launch_bounds__(256) void qkv_gemm(
    const bf16* __restrict__ x,
    const bf16* __restrict__ Wq, const float* __restrict__ bq,
    const bf16* __restrict__ Wk, const float* __restrict__ bk,
    const bf16* __restrict__ Wv, const float* __restrict__ bv,
    bf16* __restrict__ qo, bf16* __restrict__ ko, bf16* __restrict__ vt)
{
    __shared__ __align__(16) bf16 As[128*32];
    __shared__ __align__(16) bf16 Bs[128*32];

    const int tid  = threadIdx.x;
    const int w    = tid >> 6, lane = tid & 63;
    const int g    = lane >> 4, c16 = lane & 15;
    const int wr   = w >> 1,    wc  = w & 1;
    const int mtile = blockIdx.x, ntile = blockIdx.y;
    const int wsel  = ntile >> 3;                 // 0=Q 1=K 2=V (uniform per block)
    const bf16*  W    = (wsel==0) ? Wq : (wsel==1 ? Wk : Wv);
    const float* bias = (wsel==0) ? bq : (wsel==1 ? bk : bv);
    const float oscale = (wsel==0) ? KSCQ : 1.0f;
    const int nbase  = (ntile & 7) * 128;

    const bf16* ag = x + (size_t)(mtile*128)*C_;
    const bf16* bg = W + (size_t)nbase*C_;

    floatx4 acc[4][4] = {};

    for (int k0 = 0; k0 < C_; k0 += 32) {
        #pragma unroll
        for (int p = 0; p < 2; ++p) {
            int cb = p*256 + w*64;        // wave-uniform chunk base
            int c  = cb + lane;           // this lane's chunk: row=c>>2, colgrp=c&3
            gl2lds16(ag + (size_t)(c>>2)*C_ + k0 + (c&3)*8, As + cb*8);
            gl2lds16(bg + (size_t)(c>>2)*C_ + k0 + (c&3)*8, Bs + cb*8);
        }
        __syncthreads();

        short8 af[4], bfr[4];
        #pragma unroll
        for (int i = 0; i < 4; ++i)
            af[i] = *(const short8*)(As + (wr*64 + i*16 + c16)*32 + g*8);
        #pragma unroll
        for (int j = 0; j < 4; ++j)
            bfr[j] = *(const short8*)(Bs + (wc*64 + j*16 + c16)*32 + g*8);
        #pragma unroll
        for (int i = 0; i < 4; ++i)
            #pragma unroll
            for (int j = 0; j < 4; ++j)
                acc[i][j] = __builtin_amdgcn_mfma_f32_16x16x32_bf16(af[i], bfr[j], acc[i][j], 0, 0, 0);
        __syncthreads();
    }

    // Epilogue. C/D layout: row=(lane>>4)*4+reg, col=lane&15.
    #pragma unroll
    for (int i = 0; i < 4; ++i) {
        int m0 = mtile*128 + wr*64 + i*16 + g*4;     // 4 consecutive rows m0..m0+3
        #pragma unroll
        for (int j = 0; j < 4; ++j) {
            int n = nbase + wc*64 + j*16 + c16;      // output channel 0..1023
            float bvf = bias[n];
            if (wsel == 2) {
                // V transposed: vt[b][h][hd][t]; 4 regs = 4 consecutive t -> one 8B store
                int bb = m0 >> 11, t0 = m0 & (T_-1);
                int hh = n >> 6,  hd = n & 63;
                union { bf16 hv[4]; uint2 u; } tmp;
                #pragma unroll
                for (int r = 0; r < 4; ++r) tmp.hv[r] = __float2bfloat16(acc[i][j][r] + bvf);
                *(uint2*)(vt + ((size_t)((bb*H_ + hh)*64 + hd))*T_ + t0) = tmp.u;
            } else {
                bf16* dst = (wsel==0) ? qo : ko;
                #pragma unroll
                for (int r = 0; r < 4; ++r)
                    dst[(size_t)(m0+r)*C_ + n] = __float2bfloat16((acc[i][j][r] + bvf) * oscale);
            }
        }
    }
}

// ---------------------------------------------------------------------------
// Kernel B v7: causal flash attention — barrier-free register-direct waves.
// 1024 blocks x 64 threads = 1024 independent waves (1/SIMD, ~512 VGPR
// budget). Wave = pair of 32-row q-tiles (j, 63-j) -> 17 K-tile iters for
// every wave. K/V MFMA fragments are loaded STRAIGHT from global (frag =
// 16B/lane; L2/L3-cached) -- no K/V LDS, no DMA, no __syncthreads.
// Only LDS use: tiny wave-private Ps buffer for the P layout round-trip
// (wave-local lgkm ordering; rt-double-buffered).
// ---------------------------------------------------------------------------
__global__ __launch_bounds__(64, 1) void attn(
    const bf16* __restrict__ q, const bf16* __restrict__ k,
    const bf16* __restrict__ vt, bf16* __restrict__ y)
{
    __shared__ __align__(16) bf16 Ps[2][16*PSTR];   // 8.7 KB, wave-private

    const int lane = threadIdx.x & 63;
    const int g = lane >> 4, c16 = lane & 15;
    const int W = blockIdx.x;
    const int p = W & 31, bh = W >> 5;
    const int h = bh & 15, b = bh >> 4;

    const bf16* kbase = k  + ((size_t)(b*T_))*C_ + h*64;
    const bf16* vbase = vt + ((size_t)(b*H_ + h))*64*T_;
    const short ONEB = 0x3F80;                      // bf16 1.0
    const short8 ones = {ONEB,ONEB,ONEB,ONEB,ONEB,ONEB,ONEB,ONEB};

    #pragma unroll 1
    for (int seg = 0; seg < 2; ++seg) {
        const int j  = seg ? p : 63 - p;            // long segment first
        const int q0 = j * 32;
        const int nit = (j >> 2) + 1;               // # 128-key tiles (causal)

        // Q frags (B operand), 32 q-rows = 2 rt: [q=c16][d=g*8+..], pre-scaled
        short8 aq[2][2];
        #pragma unroll
        for (int rt = 0; rt < 2; ++rt)
            #pragma unroll
            for (int kg = 0; kg < 2; ++kg)
                aq[rt][kg] = *(const short8*)(q + ((size_t)(b*T_ + q0 + rt*16 + c16))*C_
                                                + h*64 + kg*32 + g*8);

        floatx4 accO[2][4] = {};
        floatx4 lacc[2] = {};
        float m_l[2] = {-1e30f, -1e30f};

        #pragma unroll 1
        for (int kt = 0; kt < nit; ++kt) {
            // K fragments direct from global: frag(ct,kg) = 16B/lane
            const bf16* kp = kbase + (size_t)(kt*128 + c16)*C_ + g*8;
            short8 kb[8][2];
            #pragma unroll
            for (int ct = 0; ct < 8; ++ct)
                #pragma unroll
                for (int kg = 0; kg < 2; ++kg)
                    kb[ct][kg] = *(const short8*)(kp + (size_t)(ct*16)*C_ + kg*32);
            // V fragments direct from global (independent of S; issued early)
            const bf16* vp = vbase + (size_t)c16*T_ + kt*128 + g*8;
            short8 vb[4][4];
            #pragma unroll
            for (int ks = 0; ks < 4; ++ks)
                #pragma unroll
                for (int nt = 0; nt < 4; ++nt)
                    vb[ks][nt] = *(const short8*)(vp + (size_t)(nt*16)*T_ + ks*32);

            // S^T = K Q^T : D[key=g*4+r (per ct)][q=c16]  (log2-scaled)
            floatx4 s[2][8];
            #pragma unroll
            for (int rt = 0; rt < 2; ++rt)
                #pragma unroll
                for (int ct = 0; ct < 8; ++ct) {
                    floatx4 a = {0.f, 0.f, 0.f, 0.f};
                    a = __builtin_amdgcn_mfma_f32_16x16x32_bf16(kb[ct][0], aq[rt][0], a, 0, 0, 0);
                    a = __builtin_amdgcn_mfma_f32_16x16x32_bf16(kb[ct][1], aq[rt][1], a, 0, 0, 0);
                    s[rt][ct] = a;
                }

            if (kt == nit-1) {   // causal mask: key > q (lane-local operands)
                #pragma unroll
                for (int rt = 0; rt < 2; ++rt) {
                    int qglob = q0 + rt*16 + c16;
                    #pragma unroll
                    for (int ct = 0; ct < 8; ++ct)
                        #pragma unroll
                        for (int r = 0; r < 4; ++r) {
                            int key = kt*128 + ct*16 + g*4 + r;
                            if (key > qglob) s[rt][ct][r] = -1e30f;
                        }
                }
            }

            #pragma unroll
            for (int rt = 0; rt < 2; ++rt) {
                // tree max over 32 in-lane values + 2 shfls across g-lanes
                float cm[8];
                #pragma unroll
                for (int ct = 0; ct < 8; ++ct)
                    cm[ct] = fmaxf(fmaxf(s[rt][ct][0], s[rt][ct][1]),
                                   fmaxf(s[rt][ct][2], s[rt][ct][3]));
                float tmax = fmaxf(fmaxf(fmaxf(cm[0], cm[1]), fmaxf(cm[2], cm[3])),
                                   fmaxf(fmaxf(cm[4], cm[5]), fmaxf(cm[6], cm[7])));
                tmax = fmaxf(tmax, __shfl_xor(tmax, 16));
                tmax = fmaxf(tmax, __shfl_xor(tmax, 32));
                float mn = fmaxf(m_l[rt], tmax);
                float alpha = exp2f(m_l[rt] - mn);
                m_l[rt] = mn;

                // rescale O, l by alpha broadcast to C-layout rows (q=g*4+r)
                float ar[4];
                #pragma unroll
                for (int r = 0; r < 4; ++r) ar[r] = __shfl(alpha, g*4 + r);
                #pragma unroll
                for (int r = 0; r < 4; ++r) {
                    lacc[rt][r] *= ar[r];
                    #pragma unroll
                    for (int nt = 0; nt < 4; ++nt) accO[rt][nt][r] *= ar[r];
                }

                // exp + pack all 128 keys for this rt, single LDS round-trip
                #pragma unroll
                for (int ct = 0; ct < 8; ++ct) {
                    float p0 = exp2f(s[rt][ct][0] - mn);
                    float p1 = exp2f(s[rt][ct][1] - mn);
                    float p2 = exp2f(s[rt][ct][2] - mn);
                    float p3 = exp2f(s[rt][ct][3] - mn);
                    union { __hip_bfloat162 h2[2]; uint2 u; } pk;
                    pk.h2[0] = __float22bfloat162_rn(float2{p0, p1});
                    pk.h2[1] = __float22bfloat162_rn(float2{p2, p3});
                    *(uint2*)(Ps[rt] + c16*PSTR + ct*16 + g*4) = pk.u;
                }
                short8 pa[4];
                #pragma unroll
                for (int ks = 0; ks < 4; ++ks)
                    pa[ks] = *(const short8*)(Ps[rt] + c16*PSTR + ks*32 + g*8);
                #pragma unroll
                for (int ks = 0; ks < 4; ++ks) {
                    lacc[rt] = __builtin_amdgcn_mfma_f32_16x16x32_bf16(pa[ks], ones, lacc[rt], 0, 0, 0);
                    #pragma unroll
                    for (int nt = 0; nt < 4; ++nt)
                        accO[rt][nt] = __builtin_amdgcn_mfma_f32_16x16x32_bf16(pa[ks], vb[ks][nt], accO[rt][nt], 0, 0, 0);
                }
            }
        }

        // epilogue: y = O * (1/l); l already in accO row layout
        #pragma unroll
        for (int rt = 0; rt < 2; ++rt) {
            float ir[4];
            #pragma unroll
            for (int r = 0; r < 4; ++r) ir[r] = __builtin_amdgcn_rcpf(lacc[rt][r]);
            #pragma unroll
            for (int nt = 0; nt < 4; ++nt)
                #pragma unroll
                for (int r = 0; r < 4; ++r) {
                    int row = q0 + rt*16 + g*4 + r;
                    float o = accO[rt][nt][r] * ir[r];
                    y[((size_t)(b*T_ + row))*C_ + h*64 + nt*16 + c16] = __float2bfloat16(o);
                }
        }
    }
}

// ---------------------------------------------------------------------------
// Kernel C: output projection. out = y_att @ Wp^T + bp (f32 output). Grid (32, 8).
// ---------------------------------------------------------------------------
__global__ __launch_bounds__(256) void proj_gemm(
    const bf16* __restrict__ yin, const bf16* __restrict__ Wp, const float* __restrict__ bp,
    float* __restrict__ out)
{
    __shared__ __align__(16) bf16 As[128*32];
    __shared__ __align__(16) bf16 Bs[128*32];

    const int tid = threadIdx.x;
    const int w = tid >> 6, lane = tid & 63;
    const int g = lane >> 4, c16 = lane & 15;
    const int wr = w >> 1, wc = w & 1;
    const int mtile = blockIdx.x, ntile = blockIdx.y;
    const int nbase = ntile * 128;

    const bf16* ag = yin + (size_t)(mtile*128)*C_;
    const bf16* bg = Wp  + (size_t)nbase*C_;

    floatx4 acc[4][4] = {};

    for (int k0 = 0; k0 < C_; k0 += 32) {
        #pragma unroll
        for (int p = 0; p < 2; ++p) {
            int cb = p*256 + w*64;
            int c  = cb + lane;
            gl2lds16(ag + (size_t)(c>>2)*C_ + k0 + (c&3)*8, As + cb*8);
            gl2lds16(bg + (size_t)(c>>2)*C_ + k0 + (c&3)*8, Bs + cb*8);
        }
        __syncthreads();

        short8 af[4], bfr[4];
        #pragma unroll
        for (int i = 0; i < 4; ++i)
            af[i] = *(const short8*)(As + (wr*64 + i*16 + c16)*32 + g*8);
        #pragma unroll
        for (int j = 0; j < 4; ++j)
            bfr[j] = *(const short8*)(Bs + (wc*64 + j*16 + c16)*32 + g*8);
        #pragma unroll
        for (int i = 0; i < 4; ++i)
            #pragma unroll
            for (int j = 0; j < 4; ++j)
                acc[i][j] = __builtin_amdgcn_mfma_f32_16x16x32_bf16(af[i], bfr[j], acc[i][j], 0, 0, 0);
        __syncthreads();
    }

    #pragma unroll
    for (int i = 0; i < 4; ++i) {
        int m0 = mtile*128 + wr*64 + i*16 + g*4;
        #pragma unroll
        for (int j = 0; j < 4; ++j) {
            int n = nbase + wc*64 + j*16 + c16;
            float bvf = bp[n];
            #pragma unroll
            for (int r = 0; r < 4; ++r)
                out[(size_t)(m0+r)*C_ + n] = acc[i][j][r] + bvf;
        }
    }
}

extern "C" void kernel_launch(void* const* d_in, const int* in_sizes, int n_in,
                              void* d_out, int out_size, void* d_ws, size_t ws_size,
                              hipStream_t stream) {
    const float* x  = (const float*)d_in[0];
    const float* Wq = (const float*)d_in[1];
    const float* bq = (const float*)d_in[2];
    const float* Wk = (const float*)d_in[3];
    const float* bk = (const float*)d_in[4];
    const float* Wv = (const float*)d_in[5];
    const float* bv = (const float*)d_in[6];
    const float* Wp = (const float*)d_in[7];
    const float* bp = (const float*)d_in[8];

    // workspace layout (bf16 elements)
    bf16* xb  = (bf16*)d_ws;          // 4M
    bf16* wqb = xb  + NX_;            // 1M
    bf16* wkb = wqb + NW_;            // 1M
    bf16* wvb = wkb + NW_;            // 1M
    bf16* wpb = wvb + NW_;            // 1M
    bf16* qw  = wpb + NW_;            // 4M
    bf16* kw  = qw  + NX_;            // 4M
    bf16* vt  = kw  + NX_;            // 4M
    bf16* yw  = vt  + NX_;            // 4M  -> total 24M bf16 = 48 MB

    const int cvt_blocks = (int)((NX_ + 4*NW_) / (4*256));   // 8192
    cvt_f32_bf16<<<cvt_blocks, 256, 0, stream>>>(x, Wq, Wk, Wv, Wp, xb, wqb, wkb, wvb, wpb);
    qkv_gemm<<<dim3(32, 24), 256, 0, stream>>>(xb, wqb, bq, wkb, bk, wvb, bv, qw, kw, vt);
    attn    <<<1024, 64, 0, stream>>>(qw, kw, vt, yw);
    proj_gemm<<<dim3(32, 8), 256, 0, stream>>>(yw, wpb, bp, (float*)d_out);
}

// Round 9
// 217.134 us; speedup vs baseline: 1.0545x; 1.0545x over previous
//
#include <hip/hip_runtime.h>
#include <hip/hip_bf16.h>

using bf16 = __hip_bfloat16;
typedef __attribute__((ext_vector_type(8))) short short8;   // 8 bf16 = 4 VGPRs (MFMA A/B frag)
typedef __attribute__((ext_vector_type(4))) float floatx4;  // MFMA C/D frag

#define B_  2
#define T_  2048
#define C_  1024
#define H_  16
#define HD_ 64
#define BT_ (B_*T_)
#define NX_ ((size_t)BT_*C_)   /* 4M elems */
#define NW_ ((size_t)C_*C_)    /* 1M elems */
#define PSTR 136               /* Ps row stride in elems: 272B, 16B-aligned */
#define KSCQ 0.1803368801f     /* (1/sqrt(64)) * log2(e), folded into Q at qkv epilogue */

// async global->LDS, 16B per lane. LDS dest is wave-uniform base; lane i lands at base + i*16B.
__device__ __forceinline__ void gl2lds16(const bf16* g, bf16* l) {
    __builtin_amdgcn_global_load_lds((const __attribute__((address_space(1))) unsigned int*)g,
                                     (__attribute__((address_space(3))) unsigned int*)l,
                                     16, 0, 0);
}

// ---------------------------------------------------------------------------
// Kernel 0: f32 -> bf16 conversion for x and the 4 weight matrices.
// ---------------------------------------------------------------------------
__global__ __launch_bounds__(256) void cvt_f32_bf16(
    const float* __restrict__ x,
    const float* __restrict__ Wq, const float* __restrict__ Wk,
    const float* __restrict__ Wv, const float* __restrict__ Wp,
    bf16* __restrict__ xb, bf16* __restrict__ wqb, bf16* __restrict__ wkb,
    bf16* __restrict__ wvb, bf16* __restrict__ wpb)
{
    size_t i4 = ((size_t)blockIdx.x * 256 + threadIdx.x) * 4;
    const float* src; bf16* dst; size_t off;
    if (i4 < NX_) { src = x; dst = xb; off = i4; }
    else {
        size_t j = i4 - NX_;
        int r = (int)(j >> 20);
        off = j & (NW_ - 1);
        src = (r==0) ? Wq : (r==1) ? Wk : (r==2) ? Wv : Wp;
        dst = (r==0) ? wqb : (r==1) ? wkb : (r==2) ? wvb : wpb;
    }
    float4 v = *(const float4*)(src + off);
    union { bf16 h[4]; uint2 u; } o;
    o.h[0] = __float2bfloat16(v.x); o.h[1] = __float2bfloat16(v.y);
    o.h[2] = __float2bfloat16(v.z); o.h[3] = __float2bfloat16(v.w);
    *(uint2*)(dst + off) = o.u;
}

// ---------------------------------------------------------------------------
// Kernel A: fused QKV projection.  y = x @ W^T + b for W in {Wq,Wk,Wv}.
// Grid (32 mtiles, 24 ntiles). ntile/8 selects the weight. 128x128 tile, BK=32.
// Q stored PRE-SCALED by KSCQ; Q,K stored [B,T,C]; V stored [B,H,HD,T].
// ---------------------------------------------------------------------------
__global__ __launch_bounds__(256) void qkv_gemm(
    const bf16* __restrict__ x,
    const bf16* __restrict__ Wq, const float* __restrict__ bq,
    const bf16* __restrict__ Wk, const float* __restrict__ bk,
    const bf16* __restrict__ Wv, const float* __restrict__ bv,
    bf16* __restrict__ qo, bf16* __restrict__ ko, bf16* __restrict__ vt)
{
    __shared__ __align__(16) bf16 As[128*32];
    __shared__ __align__(16) bf16 Bs[128*32];

    const int tid  = threadIdx.x;
    const int w    = tid >> 6, lane = tid & 63;
    const int g    = lane >> 4, c16 = lane & 15;
    const int wr   = w >> 1,    wc  = w & 1;
    const int mtile = blockIdx.x, ntile = blockIdx.y;
    const int wsel  = ntile >> 3;                 // 0=Q 1=K 2=V (uniform per block)
    const bf16*  W    = (wsel==0) ? Wq : (wsel==1 ? Wk : Wv);
    const float* bias = (wsel==0) ? bq : (wsel==1 ? bk : bv);
    const float oscale = (wsel==0) ? KSCQ : 1.0f;
    const int nbase  = (ntile & 7) * 128;

    const bf16* ag = x + (size_t)(mtile*128)*C_;
    const bf16* bg = W + (size_t)nbase*C_;

    floatx4 acc[4][4] = {};

    for (int k0 = 0; k0 < C_; k0 += 32) {
        #pragma unroll
        for (int p = 0; p < 2; ++p) {
            int cb = p*256 + w*64;        // wave-uniform chunk base
            int c  = cb + lane;           // this lane's chunk: row=c>>2, colgrp=c&3
            gl2lds16(ag + (size_t)(c>>2)*C_ + k0 + (c&3)*8, As + cb*8);
            gl2lds16(bg + (size_t)(c>>2)*C_ + k0 + (c&3)*8, Bs + cb*8);
        }
        __syncthreads();

        short8 af[4], bfr[4];
        #pragma unroll
        for (int i = 0; i < 4; ++i)
            af[i] = *(const short8*)(As + (wr*64 + i*16 + c16)*32 + g*8);
        #pragma unroll
        for (int j = 0; j < 4; ++j)
            bfr[j] = *(const short8*)(Bs + (wc*64 + j*16 + c16)*32 + g*8);
        #pragma unroll
        for (int i = 0; i < 4; ++i)
            #pragma unroll
            for (int j = 0; j < 4; ++j)
                acc[i][j] = __builtin_amdgcn_mfma_f32_16x16x32_bf16(af[i], bfr[j], acc[i][j], 0, 0, 0);
        __syncthreads();
    }

    // Epilogue. C/D layout: row=(lane>>4)*4+reg, col=lane&15.
    #pragma unroll
    for (int i = 0; i < 4; ++i) {
        int m0 = mtile*128 + wr*64 + i*16 + g*4;     // 4 consecutive rows m0..m0+3
        #pragma unroll
        for (int j = 0; j < 4; ++j) {
            int n = nbase + wc*64 + j*16 + c16;      // output channel 0..1023
            float bvf = bias[n];
            if (wsel == 2) {
                // V transposed: vt[b][h][hd][t]; 4 regs = 4 consecutive t -> one 8B store
                int bb = m0 >> 11, t0 = m0 & (T_-1);
                int hh = n >> 6,  hd = n & 63;
                union { bf16 hv[4]; uint2 u; } tmp;
                #pragma unroll
                for (int r = 0; r < 4; ++r) tmp.hv[r] = __float2bfloat16(acc[i][j][r] + bvf);
                *(uint2*)(vt + ((size_t)((bb*H_ + hh)*64 + hd))*T_ + t0) = tmp.u;
            } else {
                bf16* dst = (wsel==0) ? qo : ko;
                #pragma unroll
                for (int r = 0; r < 4; ++r)
                    dst[(size_t)(m0+r)*C_ + n] = __float2bfloat16((acc[i][j][r] + bvf) * oscale);
            }
        }
    }
}

// ---------------------------------------------------------------------------
// Kernel B v8: causal flash attention — register-direct + 2-way K-split.
// 1024 blocks x 128 thr = 2 waves/block -> 2048 waves = 2/SIMD (fixes r8's
// 1-wave/SIMD latency starvation). Block = pair of 32-row q-tiles (63-p, p)
// = 17 kt tiles total; wave w takes kt = w, w+2, ... of each segment (online
// softmax is subset-order agnostic). K/V frags load straight from global
// (L2-cached; no K/V LDS, no per-iter barriers). Segment-end merge in LDS:
// m=max, a_w=exp2(m_w-m), O=sum O_w a_w, l=sum l_w a_w  (2 barriers/segment).
// ---------------------------------------------------------------------------
__global__ __launch_bounds__(128, 2) void attn(
    const bf16* __restrict__ q, const bf16* __restrict__ k,
    const bf16* __restrict__ vt, bf16* __restrict__ y)
{
    __shared__ __align__(16) bf16    Ps[2][2][16*PSTR];  // [wave][rt]  17.0 KB
    __shared__ __align__(16) floatx4 MO[2][2][4][64];    // O partials  16 KB
    __shared__ __align__(16) floatx4 ML[2][2][64];       // l partials   4 KB
    __shared__               float   Mm[2][2][16];       // m partials  256 B

    const int tid = threadIdx.x, w = tid >> 6, lane = tid & 63;
    const int g = lane >> 4, c16 = lane & 15;
    const int blk = blockIdx.x;
    const int p = blk & 31, bh = blk >> 5;
    const int h = bh & 15, b = bh >> 4;

    const bf16* kbase = k  + ((size_t)(b*T_))*C_ + h*64;
    const bf16* vbase = vt + ((size_t)(b*H_ + h))*64*T_;
    const short ONEB = 0x3F80;                      // bf16 1.0
    const short8 ones = {ONEB,ONEB,ONEB,ONEB,ONEB,ONEB,ONEB,ONEB};

    #pragma unroll 1
    for (int seg = 0; seg < 2; ++seg) {
        const int j  = seg ? p : 63 - p;            // long segment first
        const int q0 = j * 32;
        const int nit = (j >> 2) + 1;               // # 128-key tiles (causal)

        // Q frags (B operand), 32 q-rows = 2 rt: [q=c16][d=g*8+..], pre-scaled
        short8 aq[2][2];
        #pragma unroll
        for (int rt = 0; rt < 2; ++rt)
            #pragma unroll
            for (int kg = 0; kg < 2; ++kg)
                aq[rt][kg] = *(const short8*)(q + ((size_t)(b*T_ + q0 + rt*16 + c16))*C_
                                                + h*64 + kg*32 + g*8);

        floatx4 accO[2][4] = {};
        floatx4 lacc[2] = {};
        float m_l[2] = {-1e30f, -1e30f};

        #pragma unroll 1
        for (int kt = w; kt < nit; kt += 2) {       // 2-way K-split across waves
            // K fragments direct from global: frag(ct,kg) = 16B/lane
            const bf16* kp = kbase + (size_t)(kt*128 + c16)*C_ + g*8;
            short8 kb[8][2];
            #pragma unroll
            for (int ct = 0; ct < 8; ++ct)
                #pragma unroll
                for (int kg = 0; kg < 2; ++kg)
                    kb[ct][kg] = *(const short8*)(kp + (size_t)(ct*16)*C_ + kg*32);
            // V fragments direct from global (independent of S; issued early)
            const bf16* vp = vbase + (size_t)c16*T_ + kt*128 + g*8;
            short8 vb[4][4];
            #pragma unroll
            for (int ks = 0; ks < 4; ++ks)
                #pragma unroll
                for (int nt = 0; nt < 4; ++nt)
                    vb[ks][nt] = *(const short8*)(vp + (size_t)(nt*16)*T_ + ks*32);

            // S^T = K Q^T : D[key=g*4+r (per ct)][q=c16]  (log2-scaled)
            floatx4 s[2][8];
            #pragma unroll
            for (int rt = 0; rt < 2; ++rt)
                #pragma unroll
                for (int ct = 0; ct < 8; ++ct) {
                    floatx4 a = {0.f, 0.f, 0.f, 0.f};
                    a = __builtin_amdgcn_mfma_f32_16x16x32_bf16(kb[ct][0], aq[rt][0], a, 0, 0, 0);
                    a = __builtin_amdgcn_mfma_f32_16x16x32_bf16(kb[ct][1], aq[rt][1], a, 0, 0, 0);
                    s[rt][ct] = a;
                }

            if (kt == nit-1) {   // causal mask: key > q (lane-local operands)
                #pragma unroll
                for (int rt = 0; rt < 2; ++rt) {
                    int qglob = q0 + rt*16 + c16;
                    #pragma unroll
                    for (int ct = 0; ct < 8; ++ct)
                        #pragma unroll
                        for (int r = 0; r < 4; ++r) {
                            int key = kt*128 + ct*16 + g*4 + r;
                            if (key > qglob) s[rt][ct][r] = -1e30f;
                        }
                }
            }

            #pragma unroll
            for (int rt = 0; rt < 2; ++rt) {
                // tree max over 32 in-lane values + 2 shfls across g-lanes
                float cm[8];
                #pragma unroll
                for (int ct = 0; ct < 8; ++ct)
                    cm[ct] = fmaxf(fmaxf(s[rt][ct][0], s[rt][ct][1]),
                                   fmaxf(s[rt][ct][2], s[rt][ct][3]));
                float tmax = fmaxf(fmaxf(fmaxf(cm[0], cm[1]), fmaxf(cm[2], cm[3])),
                                   fmaxf(fmaxf(cm[4], cm[5]), fmaxf(cm[6], cm[7])));
                tmax = fmaxf(tmax, __shfl_xor(tmax, 16));
                tmax = fmaxf(tmax, __shfl_xor(tmax, 32));
                float mn = fmaxf(m_l[rt], tmax);
                float alpha = exp2f(m_l[rt] - mn);
                m_l[rt] = mn;

                // rescale O, l by alpha broadcast to C-layout rows (q=g*4+r)
                float ar[4];
                #pragma unroll
                for (int r = 0; r < 4; ++r) ar[r] = __shfl(alpha, g*4 + r);
                #pragma unroll
                for (int r = 0; r < 4; ++r) {
                    lacc[rt][r] *= ar[r];
                    #pragma unroll
                    for (int nt = 0; nt < 4; ++nt) accO[rt][nt][r] *= ar[r];
                }

                // exp + pack all 128 keys for this rt, wave-private LDS round-trip
                #pragma unroll
                for (int ct = 0; ct < 8; ++ct) {
                    float p0 = exp2f(s[rt][ct][0] - mn);
                    float p1 = exp2f(s[rt][ct][1] - mn);
                    float p2 = exp2f(s[rt][ct][2] - mn);
                    float p3 = exp2f(s[rt][ct][3] - mn);
                    union { __hip_bfloat162 h2[2]; uint2 u; } pk;
                    pk.h2[0] = __float22bfloat162_rn(float2{p0, p1});
                    pk.h2[1] = __float22bfloat162_rn(float2{p2, p3});
                    *(uint2*)(Ps[w][rt] + c16*PSTR + ct*16 + g*4) = pk.u;
                }
                short8 pa[4];
                #pragma unroll
                for (int ks = 0; ks < 4; ++ks)
                    pa[ks] = *(const short8*)(Ps[w][rt] + c16*PSTR + ks*32 + g*8);
                #pragma unroll
                for (int ks = 0; ks < 4; ++ks) {
                    lacc[rt] = __builtin_amdgcn_mfma_f32_16x16x32_bf16(pa[ks], ones, lacc[rt], 0, 0, 0);
                    #pragma unroll
                    for (int nt = 0; nt < 4; ++nt)
                        accO[rt][nt] = __builtin_amdgcn_mfma_f32_16x16x32_bf16(pa[ks], vb[ks][nt], accO[rt][nt], 0, 0, 0);
                }
            }
        }

        // publish partials
        #pragma unroll
        for (int rt = 0; rt < 2; ++rt) {
            if (g == 0) Mm[w][rt][c16] = m_l[rt];
            ML[w][rt][lane] = lacc[rt];
            #pragma unroll
            for (int nt = 0; nt < 4; ++nt) MO[w][rt][nt][lane] = accO[rt][nt];
        }
        __syncthreads();

        // merge + write: wave w handles row-tile rt = w
        {
            const int rt = w;
            float aA[4], aB[4];
            #pragma unroll
            for (int r = 0; r < 4; ++r) {
                float mA = Mm[0][rt][g*4 + r];
                float mB = Mm[1][rt][g*4 + r];
                float mm = fmaxf(mA, mB);
                aA[r] = exp2f(mA - mm);
                aB[r] = exp2f(mB - mm);
            }
            floatx4 lA = ML[0][rt][lane], lB = ML[1][rt][lane];
            float ir[4];
            #pragma unroll
            for (int r = 0; r < 4; ++r)
                ir[r] = __builtin_amdgcn_rcpf(lA[r]*aA[r] + lB[r]*aB[r]);
            #pragma unroll
            for (int nt = 0; nt < 4; ++nt) {
                floatx4 OA = MO[0][rt][nt][lane], OB = MO[1][rt][nt][lane];
                #pragma unroll
                for (int r = 0; r < 4; ++r) {
                    int row = q0 + rt*16 + g*4 + r;
                    float o = (OA[r]*aA[r] + OB[r]*aB[r]) * ir[r];
                    y[((size_t)(b*T_ + row))*C_ + h*64 + nt*16 + c16] = __float2bfloat16(o);
                }
            }
        }
        __syncthreads();   // buffers reused by next segment
    }
}

// ---------------------------------------------------------------------------
// Kernel C v2: output projection. out = y_att @ Wp^T + bp (f32 output).
// 64x128 tile -> grid (64, 8) = 512 blocks = 2/CU (was 256 = 1/CU: latency
// fully exposed). 4 waves as 2x2 of 32x64; acc 2x4 per wave.
// ---------------------------------------------------------------------------
__global__ __launch_bounds__(256) void proj_gemm(
    const bf16* __restrict__ yin, const bf16* __restrict__ Wp, const float* __restrict__ bp,
    float* __restrict__ out)
{
    __shared__ __align__(16) bf16 As[64*32];
    __shared__ __align__(16) bf16 Bs[128*32];

    const int tid = threadIdx.x;
    const int w = tid >> 6, lane = tid & 63;
    const int g = lane >> 4, c16 = lane & 15;
    const int wr = w >> 1, wc = w & 1;
    const int mtile = blockIdx.x, ntile = blockIdx.y;
    const int nbase = ntile * 128;

    const bf16* ag = yin + (size_t)(mtile*64)*C_;
    const bf16* bg = Wp  + (size_t)nbase*C_;

    floatx4 acc[2][4] = {};

    for (int k0 = 0; k0 < C_; k0 += 32) {
        {   // A: 64x32 = 256 chunks, one DMA per thread
            int cb = w*64;
            int c  = cb + lane;
            gl2lds16(ag + (size_t)(c>>2)*C_ + k0 + (c&3)*8, As + cb*8);
        }
        #pragma unroll
        for (int p = 0; p < 2; ++p) {   // B: 128x32 = 512 chunks
            int cb = p*256 + w*64;
            int c  = cb + lane;
            gl2lds16(bg + (size_t)(c>>2)*C_ + k0 + (c&3)*8, Bs + cb*8);
        }
        __syncthreads();

        short8 af[2], bfr[4];
        #pragma unroll
        for (int i = 0; i < 2; ++i)
            af[i] = *(const short8*)(As + (wr*32 + i*16 + c16)*32 + g*8);
        #pragma unroll
        for (int j = 0; j < 4; ++j)
            bfr[j] = *(const short8*)(Bs + (wc*64 + j*16 + c16)*32 + g*8);
        #pragma unroll
        for (int i = 0; i < 2; ++i)
            #pragma unroll
            for (int j = 0; j < 4; ++j)
                acc[i][j] = __builtin_amdgcn_mfma_f32_16x16x32_bf16(af[i], bfr[j], acc[i][j], 0, 0, 0);
        __syncthreads();
    }

    #pragma unroll
    for (int i = 0; i < 2; ++i) {
        int m0 = mtile*64 + wr*32 + i*16 + g*4;
        #pragma unroll
        for (int j = 0; j < 4; ++j) {
            int n = nbase + wc*64 + j*16 + c16;
            float bvf = bp[n];
            #pragma unroll
            for (int r = 0; r < 4; ++r)
                out[(size_t)(m0+r)*C_ + n] = acc[i][j][r] + bvf;
        }
    }
}

extern "C" void kernel_launch(void* const* d_in, const int* in_sizes, int n_in,
                              void* d_out, int out_size, void* d_ws, size_t ws_size,
                              hipStream_t stream) {
    const float* x  = (const float*)d_in[0];
    const float* Wq = (const float*)d_in[1];
    const float* bq = (const float*)d_in[2];
    const float* Wk = (const float*)d_in[3];
    const float* bk = (const float*)d_in[4];
    const float* Wv = (const float*)d_in[5];
    const float* bv = (const float*)d_in[6];
    const float* Wp = (const float*)d_in[7];
    const float* bp = (const float*)d_in[8];

    // workspace layout (bf16 elements)
    bf16* xb  = (bf16*)d_ws;          // 4M
    bf16* wqb = xb  + NX_;            // 1M
    bf16* wkb = wqb + NW_;            // 1M
    bf16* wvb = wkb + NW_;            // 1M
    bf16* wpb = wvb + NW_;            // 1M
    bf16* qw  = wpb + NW_;            // 4M
    bf16* kw  = qw  + NX_;            // 4M
    bf16* vt  = kw  + NX_;            // 4M
    bf16* yw  = vt  + NX_;            // 4M  -> total 24M bf16 = 48 MB

    const int cvt_blocks = (int)((NX_ + 4*NW_) / (4*256));   // 8192
    cvt_f32_bf16<<<cvt_blocks, 256, 0, stream>>>(x, Wq, Wk, Wv, Wp, xb, wqb, wkb, wvb, wpb);
    qkv_gemm<<<dim3(32, 24), 256, 0, stream>>>(xb, wqb, bq, wkb, bk, wvb, bv, qw, kw, vt);
    attn    <<<1024, 128, 0, stream>>>(qw, kw, vt, yw);
    proj_gemm<<<dim3(64, 8), 256, 0, stream>>>(yw, wpb, bp, (float*)d_out);
}

// Round 10
// 210.075 us; speedup vs baseline: 1.0900x; 1.0336x over previous
//
#include <hip/hip_runtime.h>
#include <hip/hip_bf16.h>

using bf16 = __hip_bfloat16;
typedef __attribute__((ext_vector_type(8))) short short8;   // 8 bf16 = 4 VGPRs (MFMA A/B frag)
typedef __attribute__((ext_vector_type(4))) float floatx4;  // MFMA C/D frag

#define B_  2
#define T_  2048
#define C_  1024
#define H_  16
#define HD_ 64
#define BT_ (B_*T_)
#define NX_ ((size_t)BT_*C_)   /* 4M elems */
#define NW_ ((size_t)C_*C_)    /* 1M elems */
#define PSTR 136               /* Ps row stride in elems: 272B, 16B-aligned */
#define KSCQ 0.1803368801f     /* (1/sqrt(64)) * log2(e), folded into Q at qkv epilogue */

// async global->LDS, 16B per lane. LDS dest is wave-uniform base; lane i lands at base + i*16B.
__device__ __forceinline__ void gl2lds16(const bf16* g, bf16* l) {
    __builtin_amdgcn_global_load_lds((const __attribute__((address_space(1))) unsigned int*)g,
                                     (__attribute__((address_space(3))) unsigned int*)l,
                                     16, 0, 0);
}

// ---------------------------------------------------------------------------
// Kernel 0: f32 -> bf16 conversion for x and the 4 weight matrices.
// ---------------------------------------------------------------------------
__global__ __launch_bounds__(256) void cvt_f32_bf16(
    const float* __restrict__ x,
    const float* __restrict__ Wq, const float* __restrict__ Wk,
    const float* __restrict__ Wv, const float* __restrict__ Wp,
    bf16* __restrict__ xb, bf16* __restrict__ wqb, bf16* __restrict__ wkb,
    bf16* __restrict__ wvb, bf16* __restrict__ wpb)
{
    size_t i4 = ((size_t)blockIdx.x * 256 + threadIdx.x) * 4;
    const float* src; bf16* dst; size_t off;
    if (i4 < NX_) { src = x; dst = xb; off = i4; }
    else {
        size_t j = i4 - NX_;
        int r = (int)(j >> 20);
        off = j & (NW_ - 1);
        src = (r==0) ? Wq : (r==1) ? Wk : (r==2) ? Wv : Wp;
        dst = (r==0) ? wqb : (r==1) ? wkb : (r==2) ? wvb : wpb;
    }
    float4 v = *(const float4*)(src + off);
    union { bf16 h[4]; uint2 u; } o;
    o.h[0] = __float2bfloat16(v.x); o.h[1] = __float2bfloat16(v.y);
    o.h[2] = __float2bfloat16(v.z); o.h[3] = __float2bfloat16(v.w);
    *(uint2*)(dst + off) = o.u;
}

// ---------------------------------------------------------------------------
// Kernel A: fused QKV projection.  y = x @ W^T + b for W in {Wq,Wk,Wv}.
// Grid (32 mtiles, 24 ntiles). ntile/8 selects the weight. 128x128 tile, BK=32.
// Q stored PRE-SCALED by KSCQ; Q,K stored [B,T,C]; V stored [B,H,HD,T].
// ---------------------------------------------------------------------------
__global__ __launch_bounds__(256) void qkv_gemm(
    const bf16* __restrict__ x,
    const bf16* __restrict__ Wq, const float* __restrict__ bq,
    const bf16* __restrict__ Wk, const float* __restrict__ bk,
    const bf16* __restrict__ Wv, const float* __restrict__ bv,
    bf16* __restrict__ qo, bf16* __restrict__ ko, bf16* __restrict__ vt)
{
    __shared__ __align__(16) bf16 As[128*32];
    __shared__ __align__(16) bf16 Bs[128*32];

    const int tid  = threadIdx.x;
    const int w    = tid >> 6, lane = tid & 63;
    const int g    = lane >> 4, c16 = lane & 15;
    const int wr   = w >> 1,    wc  = w & 1;
    const int mtile = blockIdx.x, ntile = blockIdx.y;
    const int wsel  = ntile >> 3;                 // 0=Q 1=K 2=V (uniform per block)
    const bf16*  W    = (wsel==0) ? Wq : (wsel==1 ? Wk : Wv);
    const float* bias = (wsel==0) ? bq : (wsel==1 ? bk : bv);
    const float oscale = (wsel==0) ? KSCQ : 1.0f;
    const int nbase  = (ntile & 7) * 128;

    const bf16* ag = x + (size_t)(mtile*128)*C_;
    const bf16* bg = W + (size_t)nbase*C_;

    floatx4 acc[4][4] = {};

    for (int k0 = 0; k0 < C_; k0 += 32) {
        #pragma unroll
        for (int p = 0; p < 2; ++p) {
            int cb = p*256 + w*64;        // wave-uniform chunk base
            int c  = cb + lane;           // this lane's chunk: row=c>>2, colgrp=c&3
            gl2lds16(ag + (size_t)(c>>2)*C_ + k0 + (c&3)*8, As + cb*8);
            gl2lds16(bg + (size_t)(c>>2)*C_ + k0 + (c&3)*8, Bs + cb*8);
        }
        __syncthreads();

        short8 af[4], bfr[4];
        #pragma unroll
        for (int i = 0; i < 4; ++i)
            af[i] = *(const short8*)(As + (wr*64 + i*16 + c16)*32 + g*8);
        #pragma unroll
        for (int j = 0; j < 4; ++j)
            bfr[j] = *(const short8*)(Bs + (wc*64 + j*16 + c16)*32 + g*8);
        #pragma unroll
        for (int i = 0; i < 4; ++i)
            #pragma unroll
            for (int j = 0; j < 4; ++j)
                acc[i][j] = __builtin_amdgcn_mfma_f32_16x16x32_bf16(af[i], bfr[j], acc[i][j], 0, 0, 0);
        __syncthreads();
    }

    // Epilogue. C/D layout: row=(lane>>4)*4+reg, col=lane&15.
    #pragma unroll
    for (int i = 0; i < 4; ++i) {
        int m0 = mtile*128 + wr*64 + i*16 + g*4;     // 4 consecutive rows m0..m0+3
        #pragma unroll
        for (int j = 0; j < 4; ++j) {
            int n = nbase + wc*64 + j*16 + c16;      // output channel 0..1023
            float bvf = bias[n];
            if (wsel == 2) {
                // V transposed: vt[b][h][hd][t]; 4 regs = 4 consecutive t -> one 8B store
                int bb = m0 >> 11, t0 = m0 & (T_-1);
                int hh = n >> 6,  hd = n & 63;
                union { bf16 hv[4]; uint2 u; } tmp;
                #pragma unroll
                for (int r = 0; r < 4; ++r) tmp.hv[r] = __float2bfloat16(acc[i][j][r] + bvf);
                *(uint2*)(vt + ((size_t)((bb*H_ + hh)*64 + hd))*T_ + t0) = tmp.u;
            } else {
                bf16* dst = (wsel==0) ? qo : ko;
                #pragma unroll
                for (int r = 0; r < 4; ++r)
                    dst[(size_t)(m0+r)*C_ + n] = __float2bfloat16((acc[i][j][r] + bvf) * oscale);
            }
        }
    }
}

// ---------------------------------------------------------------------------
// Kernel B v9: causal flash attention — LDS-shared tiles + 32 q-rows/wave.
// Grid (16 qraw, 16 h, 2 b) = 512 blocks; qt = b ? 15-qraw : qraw so each
// CU's round-robin pair {id, id+256} carries qt and 15-qt -> uniform 17
// iters/CU. Block = 128 q-rows (4 waves x 2 rt x 16). K/V staged in LDS
// frag-contiguous (r7 layout, conflict-free, block-level reuse -> FETCH
// ~64MB); every K/V fragment read is hoisted and reused across both rt,
// halving LDS reads per q-row vs r7. LDS 66.5KB -> 2 blocks/CU.
// ---------------------------------------------------------------------------
__global__ __launch_bounds__(256, 2) void attn(
    const bf16* __restrict__ q, const bf16* __restrict__ k,
    const bf16* __restrict__ vt, bf16* __restrict__ y)
{
    __shared__ __align__(16) bf16 Ks[16*512];         // 16KB: frag f=(ct*2+kg)
    __shared__ __align__(16) bf16 Vs[16*512];         // 16KB: frag f=(ks*4+nt)
    __shared__ __align__(16) bf16 Ps[4][2][16*PSTR];  // 34.8KB: per-wave, per-rt

    const int tid = threadIdx.x, w = tid >> 6, lane = tid & 63;
    const int g = lane >> 4, c16 = lane & 15;
    const int qraw = blockIdx.x, h = blockIdx.y, b = blockIdx.z;
    const int qt = b ? 15 - qraw : qraw;          // per-CU balance (pair sums 17)
    const int nit = qt + 1;                       // # 128-key tiles (causal)
    const int q0 = qt*128 + w*32;                 // wave's q-row base

    const bf16* kbase = k  + ((size_t)(b*T_))*C_ + h*64;
    const bf16* vbase = vt + ((size_t)(b*H_ + h))*64*T_;
    const short ONEB = 0x3F80;                    // bf16 1.0
    const short8 ones = {ONEB,ONEB,ONEB,ONEB,ONEB,ONEB,ONEB,ONEB};

    // Q frags (B operand), 32 q-rows = 2 rt: [q=c16][d=g*8+..], pre-scaled
    short8 aq[2][2];
    #pragma unroll
    for (int rt = 0; rt < 2; ++rt)
        #pragma unroll
        for (int kg = 0; kg < 2; ++kg)
            aq[rt][kg] = *(const short8*)(q + ((size_t)(b*T_ + q0 + rt*16 + c16))*C_
                                            + h*64 + kg*32 + g*8);

    floatx4 accO[2][4] = {};
    floatx4 lacc[2] = {};
    float m_l[2] = {-1e30f, -1e30f};

    #pragma unroll 1
    for (int kt = 0; kt < nit; ++kt) {
        // stage 16+16 fragments; wave w stages frags f = w*4+p (wave-uniform)
        #pragma unroll
        for (int p = 0; p < 4; ++p) {
            int f = w*4 + p;
            int ctk = f >> 1, kg = f & 1;
            gl2lds16(kbase + (size_t)(kt*128 + ctk*16 + c16)*C_ + kg*32 + g*8, Ks + f*512);
            gl2lds16(vbase + (size_t)(p*16 + c16)*T_ + kt*128 + w*32 + g*8,    Vs + f*512);
        }
        __syncthreads();

        // S^T = K Q^T : each K frag read once, used for both rt
        floatx4 s[2][8];
        #pragma unroll
        for (int ct = 0; ct < 8; ++ct) {
            short8 kb0 = *(const short8*)(Ks + (ct*2 + 0)*512 + lane*8);
            short8 kb1 = *(const short8*)(Ks + (ct*2 + 1)*512 + lane*8);
            #pragma unroll
            for (int rt = 0; rt < 2; ++rt) {
                floatx4 a = {0.f, 0.f, 0.f, 0.f};
                a = __builtin_amdgcn_mfma_f32_16x16x32_bf16(kb0, aq[rt][0], a, 0, 0, 0);
                a = __builtin_amdgcn_mfma_f32_16x16x32_bf16(kb1, aq[rt][1], a, 0, 0, 0);
                s[rt][ct] = a;
            }
        }

        if (kt == nit-1) {   // causal mask: key > q (lane-local operands)
            #pragma unroll
            for (int rt = 0; rt < 2; ++rt) {
                int qglob = q0 + rt*16 + c16;
                #pragma unroll
                for (int ct = 0; ct < 8; ++ct)
                    #pragma unroll
                    for (int r = 0; r < 4; ++r) {
                        int key = kt*128 + ct*16 + g*4 + r;
                        if (key > qglob) s[rt][ct][r] = -1e30f;
                    }
            }
        }

        // online softmax per rt (tree max + 2 shfls; exp + packed P write)
        #pragma unroll
        for (int rt = 0; rt < 2; ++rt) {
            float cm[8];
            #pragma unroll
            for (int ct = 0; ct < 8; ++ct)
                cm[ct] = fmaxf(fmaxf(s[rt][ct][0], s[rt][ct][1]),
                               fmaxf(s[rt][ct][2], s[rt][ct][3]));
            float tmax = fmaxf(fmaxf(fmaxf(cm[0], cm[1]), fmaxf(cm[2], cm[3])),
                               fmaxf(fmaxf(cm[4], cm[5]), fmaxf(cm[6], cm[7])));
            tmax = fmaxf(tmax, __shfl_xor(tmax, 16));
            tmax = fmaxf(tmax, __shfl_xor(tmax, 32));
            float mn = fmaxf(m_l[rt], tmax);
            float alpha = exp2f(m_l[rt] - mn);
            m_l[rt] = mn;

            float ar[4];
            #pragma unroll
            for (int r = 0; r < 4; ++r) ar[r] = __shfl(alpha, g*4 + r);
            #pragma unroll
            for (int r = 0; r < 4; ++r) {
                lacc[rt][r] *= ar[r];
                #pragma unroll
                for (int nt = 0; nt < 4; ++nt) accO[rt][nt][r] *= ar[r];
            }

            #pragma unroll
            for (int ct = 0; ct < 8; ++ct) {
                float p0 = exp2f(s[rt][ct][0] - mn);
                float p1 = exp2f(s[rt][ct][1] - mn);
                float p2 = exp2f(s[rt][ct][2] - mn);
                float p3 = exp2f(s[rt][ct][3] - mn);
                union { __hip_bfloat162 h2[2]; uint2 u; } pk;
                pk.h2[0] = __float22bfloat162_rn(float2{p0, p1});
                pk.h2[1] = __float22bfloat162_rn(float2{p2, p3});
                *(uint2*)(Ps[w][rt] + c16*PSTR + ct*16 + g*4) = pk.u;
            }
        }

        // O += P V : each V frag read once, used for both rt
        #pragma unroll
        for (int ks = 0; ks < 4; ++ks) {
            short8 vb[4];
            #pragma unroll
            for (int nt = 0; nt < 4; ++nt)
                vb[nt] = *(const short8*)(Vs + (ks*4 + nt)*512 + lane*8);
            #pragma unroll
            for (int rt = 0; rt < 2; ++rt) {
                short8 pa = *(const short8*)(Ps[w][rt] + c16*PSTR + ks*32 + g*8);
                lacc[rt] = __builtin_amdgcn_mfma_f32_16x16x32_bf16(pa, ones, lacc[rt], 0, 0, 0);
                #pragma unroll
                for (int nt = 0; nt < 4; ++nt)
                    accO[rt][nt] = __builtin_amdgcn_mfma_f32_16x16x32_bf16(pa, vb[nt], accO[rt][nt], 0, 0, 0);
            }
        }
        __syncthreads();
    }

    // epilogue: y = O * (1/l); l in accO row layout -> no shuffles
    #pragma unroll
    for (int rt = 0; rt < 2; ++rt) {
        float ir[4];
        #pragma unroll
        for (int r = 0; r < 4; ++r) ir[r] = __builtin_amdgcn_rcpf(lacc[rt][r]);
        #pragma unroll
        for (int nt = 0; nt < 4; ++nt)
            #pragma unroll
            for (int r = 0; r < 4; ++r) {
                int row = q0 + rt*16 + g*4 + r;
                float o = accO[rt][nt][r] * ir[r];
                y[((size_t)(b*T_ + row))*C_ + h*64 + nt*16 + c16] = __float2bfloat16(o);
            }
    }
}

// ---------------------------------------------------------------------------
// Kernel C v2: output projection. out = y_att @ Wp^T + bp (f32 output).
// 64x128 tile -> grid (64, 8) = 512 blocks = 2/CU.
// ---------------------------------------------------------------------------
__global__ __launch_bounds__(256) void proj_gemm(
    const bf16* __restrict__ yin, const bf16* __restrict__ Wp, const float* __restrict__ bp,
    float* __restrict__ out)
{
    __shared__ __align__(16) bf16 As[64*32];
    __shared__ __align__(16) bf16 Bs[128*32];

    const int tid = threadIdx.x;
    const int w = tid >> 6, lane = tid & 63;
    const int g = lane >> 4, c16 = lane & 15;
    const int wr = w >> 1, wc = w & 1;
    const int mtile = blockIdx.x, ntile = blockIdx.y;
    const int nbase = ntile * 128;

    const bf16* ag = yin + (size_t)(mtile*64)*C_;
    const bf16* bg = Wp  + (size_t)nbase*C_;

    floatx4 acc[2][4] = {};

    for (int k0 = 0; k0 < C_; k0 += 32) {
        {   // A: 64x32 = 256 chunks
            int cb = w*64;
            int c  = cb + lane;
            gl2lds16(ag + (size_t)(c>>2)*C_ + k0 + (c&3)*8, As + cb*8);
        }
        #pragma unroll
        for (int p = 0; p < 2; ++p) {   // B: 128x32 = 512 chunks
            int cb = p*256 + w*64;
            int c  = cb + lane;
            gl2lds16(bg + (size_t)(c>>2)*C_ + k0 + (c&3)*8, Bs + cb*8);
        }
        __syncthreads();

        short8 af[2], bfr[4];
        #pragma unroll
        for (int i = 0; i < 2; ++i)
            af[i] = *(const short8*)(As + (wr*32 + i*16 + c16)*32 + g*8);
        #pragma unroll
        for (int j = 0; j < 4; ++j)
            bfr[j] = *(const short8*)(Bs + (wc*64 + j*16 + c16)*32 + g*8);
        #pragma unroll
        for (int i = 0; i < 2; ++i)
            #pragma unroll
            for (int j = 0; j < 4; ++j)
                acc[i][j] = __builtin_amdgcn_mfma_f32_16x16x32_bf16(af[i], bfr[j], acc[i][j], 0, 0, 0);
        __syncthreads();
    }

    #pragma unroll
    for (int i = 0; i < 2; ++i) {
        int m0 = mtile*64 + wr*32 + i*16 + g*4;
        #pragma unroll
        for (int j = 0; j < 4; ++j) {
            int n = nbase + wc*64 + j*16 + c16;
            float bvf = bp[n];
            #pragma unroll
            for (int r = 0; r < 4; ++r)
                out[(size_t)(m0+r)*C_ + n] = acc[i][j][r] + bvf;
        }
    }
}

extern "C" void kernel_launch(void* const* d_in, const int* in_sizes, int n_in,
                              void* d_out, int out_size, void* d_ws, size_t ws_size,
                              hipStream_t stream) {
    const float* x  = (const float*)d_in[0];
    const float* Wq = (const float*)d_in[1];
    const float* bq = (const float*)d_in[2];
    const float* Wk = (const float*)d_in[3];
    const float* bk = (const float*)d_in[4];
    const float* Wv = (const float*)d_in[5];
    const float* bv = (const float*)d_in[6];
    const float* Wp = (const float*)d_in[7];
    const float* bp = (const float*)d_in[8];

    // workspace layout (bf16 elements)
    bf16* xb  = (bf16*)d_ws;          // 4M
    bf16* wqb = xb  + NX_;            // 1M
    bf16* wkb = wqb + NW_;            // 1M
    bf16* wvb = wkb + NW_;            // 1M
    bf16* wpb = wvb + NW_;            // 1M
    bf16* qw  = wpb + NW_;            // 4M
    bf16* kw  = qw  + NX_;            // 4M
    bf16* vt  = kw  + NX_;            // 4M
    bf16* yw  = vt  + NX_;            // 4M  -> total 24M bf16 = 48 MB

    const int cvt_blocks = (int)((NX_ + 4*NW_) / (4*256));   // 8192
    cvt_f32_bf16<<<cvt_blocks, 256, 0, stream>>>(x, Wq, Wk, Wv, Wp, xb, wqb, wkb, wvb, wpb);
    qkv_gemm<<<dim3(32, 24), 256, 0, stream>>>(xb, wqb, bq, wkb, bk, wvb, bv, qw, kw, vt);
    attn    <<<dim3(16, H_, B_), 256, 0, stream>>>(qw, kw, vt, yw);
    proj_gemm<<<dim3(64, 8), 256, 0, stream>>>(yw, wpb, bp, (float*)d_out);
}